// Round 12
// baseline (1706.234 us; speedup 1.0000x reference)
//
#include <hip/hip_runtime.h>
#include <hip/hip_bf16.h>

#define THREADS 1024

typedef __hip_bfloat16 bf16;
typedef __attribute__((ext_vector_type(4))) float f32x4;
typedef __attribute__((ext_vector_type(16))) float f32x16;
typedef __attribute__((ext_vector_type(8))) short bf16x8;

#define MFMA32 __builtin_amdgcn_mfma_f32_32x32x16_bf16
#define Z16 f32x16{0.f,0.f,0.f,0.f,0.f,0.f,0.f,0.f,0.f,0.f,0.f,0.f,0.f,0.f,0.f,0.f}

// ---- LDS: blocks of 512 bf16 = one 32-col x 16-k B-fragment tile.
// Buffers double-slotted: read slot p=t&1, write slot q=p^1.
#define O_A1  0       // 2nt x 2kc x 2s : K=[x(2)|h1(16)|bias@18|pad]
#define O_AY  4096    // 2nt x 3kc x 2s : K=[y(36)|bias@36|pad]
#define O_AT1 10240   // 2nt x 5kc x 2s : K=[t1(64)|bias@64|pad]
#define O_A2  20480   // 2nt x 10kc x 2s: K=[l2(72)|h2(72)|bias@144|pad]
#define O_AH3 40960   // 2nt x 2kc x 2s : K=h3(32)
#define LDS_ELEMS 45056
#define LDS_BYTES (LDS_ELEMS * 2)   // 90112

__device__ __forceinline__ int blk(int KC, int nt, int kc, int slot) {
    return ((nt * KC + kc) * 2 + slot) << 9;
}
__device__ __forceinline__ int eix(int col, int kl) { // elem index in block
    return ((col | ((kl >> 3) << 5)) << 3) + (kl & 7);
}

__device__ __forceinline__ float rcp_(float x) { return __builtin_amdgcn_rcpf(x); }
__device__ __forceinline__ float exp2_(float x) {
#if __has_builtin(__builtin_amdgcn_exp2f)
    return __builtin_amdgcn_exp2f(x);
#else
    return exp2f(x);
#endif
}

// gate EW, log2e folded into weights: a = {-i*log2e, -f*log2e, 2g*log2e, -o*log2e}
// 5 exp2 + 3 rcp, no muls for the gate exps.
__device__ __forceinline__ float lstm_ew1(f32x4 a, float& cst) {
    float ei = exp2_(a[0]);
    float ef = exp2_(a[1]);
    float eg = exp2_(fminf(a[2], 115.0f));
    float eo = exp2_(a[3]);
    float c = rcp_(1.0f + ef) * cst + (eg - 1.0f) * rcp_((1.0f + ei) * (eg + 1.0f));
    cst = c;
    float ec = exp2_(fminf(c * 2.885390082f, 115.0f));
    return (ec - 1.0f) * rcp_((1.0f + eo) * (ec + 1.0f));
}

__device__ __forceinline__ ushort bfu(float f) {
    union { bf16 b; ushort u; } v; v.b = __float2bfloat16(f); return v.u;
}

// pack one K=16 weight fragment; k-map k = ((lane>>5)<<3)+j, rows = lane&31
// (self-consistent with the B-fragment layout written by eix(); errors cancel)
template <typename F>
__device__ __forceinline__ bf16x8 mk32(int lane, F val) { // val(k), k in [0,16)
    union { bf16x8 v; bf16 h[8]; } u;
#pragma unroll
    for (int j = 0; j < 8; ++j)
        u.h[j] = __float2bfloat16(val(((lane >> 5) << 3) + j));
    return u.v;
}

__global__ void __launch_bounds__(THREADS, 4)
lstm_fused(const float* __restrict__ x, const float* __restrict__ y,
           const float* __restrict__ Wih1, const float* __restrict__ Whh1,
           const float* __restrict__ bih1, const float* __restrict__ bhh1,
           const float* __restrict__ Wih2, const float* __restrict__ Whh2,
           const float* __restrict__ bih2, const float* __restrict__ bhh2,
           const float* __restrict__ Wih3, const float* __restrict__ Whh3,
           const float* __restrict__ bih3, const float* __restrict__ bhh3,
           const float* __restrict__ W1, const float* __restrict__ b1,
           const float* __restrict__ W2, const float* __restrict__ b2,
           const float* __restrict__ W3, const float* __restrict__ b3,
           const float* __restrict__ W4, const float* __restrict__ b4,
           float* __restrict__ out) {
    extern __shared__ char smem[];
    bf16* sb = (bf16*)smem;
    const int tid = threadIdx.x;
    const int wave = tid >> 6, lane = tid & 63;
    const int ln31 = lane & 31, hi = lane >> 5;
    const int b0 = blockIdx.x * 64;

    // ---- roles (same as r11) ----
    bf16x8 W[11];
#pragma unroll
    for (int i = 0; i < 11; ++i) W[i] = bf16x8{0, 0, 0, 0, 0, 0, 0, 0};

    if (wave < 9) { // LSTM2 rows n=32w+ln31, gate interleave n=4h+g, log2e folded
        int n = 32 * wave + ln31;
        int r = (n & 3) * 72 + (n >> 2);
        float bias = bih2[r] + bhh2[r];
        float sc = ((n & 3) == 2) ? 2.885390082f : -1.442695041f;
#pragma unroll
        for (int kc = 0; kc < 10; ++kc)
            W[kc] = mk32(lane, [&](int k) {
                int kg = kc * 16 + k;
                float v = kg < 72 ? Wih2[r * 72 + kg]
                       : (kg < 144 ? Whh2[r * 72 + (kg - 72)]
                       : (kg == 144 ? bias : 0.0f));
                return sc * v; });
    } else if (wave < 13) { // LSTM3
        int n = 32 * (wave - 9) + ln31;
        int r = (n & 3) * 32 + (n >> 2);
        float bias = bih3[r] + bhh3[r];
        float sc = ((n & 3) == 2) ? 2.885390082f : -1.442695041f;
        W[0] = mk32(lane, [&](int k) {
            return sc * (k < 2 ? 0.0f : Wih3[r * 88 + (k - 2)]); });
        W[1] = mk32(lane, [&](int k) {
            int kg = 16 + k;
            return sc * (kg < 18 ? Wih3[r * 88 + (kg - 2)] : (kg == 18 ? bias : 0.0f)); });
#pragma unroll
        for (int i = 0; i < 5; ++i)
            W[2 + i] = mk32(lane, [&](int k) {
                int kg = 64 + i * 16 + k;
                return sc * (kg < 72 ? 0.0f : Wih3[r * 88 + 16 + (kg - 72)]); });
#pragma unroll
        for (int i = 0; i < 2; ++i)
            W[7 + i] = mk32(lane, [&](int k) { return sc * Whh3[r * 32 + i * 16 + k]; });
        if (wave < 11) { // FC34 (unscaled)
#pragma unroll
            for (int i = 0; i < 2; ++i)
                W[9 + i] = mk32(lane, [&](int k) {
                    return (ln31 < 16) ? W3[ln31 * 32 + i * 16 + k] : 0.0f; });
        }
    } else {
        if (wave < 15) { // L1 Mtile wave-13, log2e folded
            int n = 32 * (wave - 13) + ln31;
            int r = (n & 3) * 16 + (n >> 2);
            float bias = bih1[r] + bhh1[r];
            float sc = ((n & 3) == 2) ? 2.885390082f : -1.442695041f;
            W[0] = mk32(lane, [&](int k) {
                return sc * (k < 2 ? Wih1[r * 2 + k] : Whh1[r * 16 + (k - 2)]); });
            W[1] = mk32(lane, [&](int k) {
                int kg = 16 + k;
                return sc * (kg < 18 ? Whh1[r * 16 + (kg - 2)] : (kg == 18 ? bias : 0.0f)); });
        }
        { // FC2 Mtile wave-13 (unscaled)
            int n2 = 32 * (wave - 13) + ln31;
#pragma unroll
            for (int kc = 0; kc < 5; ++kc)
                W[2 + kc] = mk32(lane, [&](int k) {
                    int kg = kc * 16 + k;
                    if (n2 >= 72) return 0.0f;
                    return kg < 64 ? W2[n2 * 64 + kg] : (kg == 64 ? b2[n2] : 0.0f); });
        }
        if (wave >= 14) { // FC1 Mtile wave-14 (unscaled)
            int f = 32 * (wave - 14) + ln31;
#pragma unroll
            for (int kc = 0; kc < 3; ++kc)
                W[7 + kc] = mk32(lane, [&](int k) {
                    int kg = kc * 16 + k;
                    return kg < 36 ? W1[f * 36 + kg] : (kg == 36 ? b1[f] : 0.0f); });
        }
    }

    // ---- zero LDS ----
    {
        int4* z = (int4*)sb;
        int4 zv = {0, 0, 0, 0};
        for (int i = tid; i < LDS_BYTES / 16; i += THREADS) z[i] = zv;
    }
    __syncthreads();
    // ---- stage y(0)->AY[s0], y(1)->AY[s1], x(0)->A1[s0], bias lanes ----
    for (int it = tid; it < 2 * 2304; it += THREADS) {
        int slot = it / 2304, r2 = it - slot * 2304;
        int m = r2 / 36, k = r2 - m * 36;
        sb[O_AY + blk(3, m >> 5, k >> 4, slot) + eix(m & 31, k & 15)] =
            __float2bfloat16(y[(size_t)(b0 + m) * 900 + slot * 36 + k]);
    }
    if (tid < 128) {
        int m = tid >> 1, k = tid & 1;
        sb[O_A1 + blk(2, m >> 5, 0, 0) + eix(m & 31, k)] =
            __float2bfloat16(x[(size_t)(b0 + m) * 50 + k]);
    }
    {
        const bf16 one = __float2bfloat16(1.0f);
        int i = tid & 127, col = i & 31, nt = (i >> 5) & 1, s = (i >> 6) & 1;
        if (tid < 128)       sb[O_A1 + blk(2, nt, 1, s) + eix(col, 2)] = one;   // k=18
        else if (tid < 256)  sb[O_AY + blk(3, nt, 2, s) + eix(col, 4)] = one;   // k=36
        else if (tid < 384)  sb[O_AT1 + blk(5, nt, 4, s) + eix(col, 0)] = one;  // k=64
        else if (tid < 512)  sb[O_A2 + blk(10, nt, 9, s) + eix(col, 0)] = one;  // k=144
    }
    __syncthreads();
    // ---- prologue FC1(0)->AT1[1], FC1(1)->AT1[0] on w14-15 ----
    if (wave >= 14) {
#pragma unroll
        for (int s = 0; s < 2; ++s) {
#pragma unroll
            for (int nt = 0; nt < 2; ++nt) {
                f32x16 acc = Z16;
#pragma unroll
                for (int kc = 0; kc < 3; ++kc) {
                    bf16x8 a = *(const bf16x8*)(sb + O_AY + blk(3, nt, kc, s) + (lane << 3));
                    acc = MFMA32(W[7 + kc], a, acc, 0, 0, 0);
                }
#pragma unroll
                for (int qq = 0; qq < 4; ++qq) {
                    int f0 = 32 * (wave - 14) + 8 * qq + 4 * hi;
                    ushort4 pk;
                    pk.x = bfu(fmaxf(acc[4 * qq + 0], 0.f));
                    pk.y = bfu(fmaxf(acc[4 * qq + 1], 0.f));
                    pk.z = bfu(fmaxf(acc[4 * qq + 2], 0.f));
                    pk.w = bfu(fmaxf(acc[4 * qq + 3], 0.f));
                    *(ushort4*)(sb + O_AT1 + blk(5, nt, f0 >> 4, s ^ 1) + eix(ln31, f0 & 15)) = pk;
                }
            }
        }
    }
    __syncthreads();
    // ---- prologue FC2(0)->A2[s0] (w13-15, reads AT1[s1]); y(2)->AY[s0] (w11-12) ----
    if (wave >= 13) {
#pragma unroll
        for (int nt = 0; nt < 2; ++nt) {
            f32x16 acc = Z16;
#pragma unroll
            for (int kc = 0; kc < 5; ++kc) {
                bf16x8 a = *(const bf16x8*)(sb + O_AT1 + blk(5, nt, kc, 1) + (lane << 3));
                acc = MFMA32(W[2 + kc], a, acc, 0, 0, 0);
            }
#pragma unroll
            for (int qq = 0; qq < 4; ++qq) {
                int n0 = 32 * (wave - 13) + 8 * qq + 4 * hi;
                if (n0 < 72) {
                    ushort4 pk;
                    pk.x = bfu(acc[4 * qq + 0]); pk.y = bfu(acc[4 * qq + 1]);
                    pk.z = bfu(acc[4 * qq + 2]); pk.w = bfu(acc[4 * qq + 3]);
                    *(ushort4*)(sb + O_A2 + blk(10, nt, n0 >> 4, 0) + eix(ln31, n0 & 15)) = pk;
                }
            }
        }
    } else if (wave == 11 || wave == 12) {
        const int half = wave - 11;
        const int m = 32 * half + (lane >> 1);
        const float* yp = y + (size_t)(b0 + m) * 900 + 2 * 36;
#pragma unroll
        for (int c = (lane & 1); c < 9; c += 2) {
            float4 v = *(const float4*)(yp + 4 * c);
            ushort4 pk;
            pk.x = bfu(v.x); pk.y = bfu(v.y); pk.z = bfu(v.z); pk.w = bfu(v.w);
            int k0 = 4 * c;
            *(ushort4*)(sb + O_AY + blk(3, half, k0 >> 4, 0) + eix(m & 31, k0 & 15)) = pk;
        }
    }
    float cS[2][4] = {};
    __syncthreads();

    // ======== main loop: ONE barrier per phase; ALL ds_writes deferred to phase end ========
    for (int t = 0; t <= 25; ++t) {
        const int p = t & 1, q = p ^ 1;

        if (wave < 9) { // ---- LSTM2(t), t<=24 ----
            if (t <= 24) {
                bf16x8 al[10], bl[10];
#pragma unroll
                for (int kc = 0; kc < 10; ++kc)
                    al[kc] = *(const bf16x8*)(sb + O_A2 + blk(10, 0, kc, p) + (lane << 3));
                f32x16 acc0 = Z16;
#pragma unroll
                for (int kc = 0; kc < 10; ++kc) acc0 = MFMA32(W[kc], al[kc], acc0, 0, 0, 0);
#pragma unroll
                for (int kc = 0; kc < 10; ++kc)
                    bl[kc] = *(const bf16x8*)(sb + O_A2 + blk(10, 1, kc, p) + (lane << 3));
                f32x16 acc1 = Z16;
#pragma unroll
                for (int kc = 0; kc < 10; ++kc) acc1 = MFMA32(W[kc], bl[kc], acc1, 0, 0, 0);
                ushort hv0[4], hv1[4];
#pragma unroll
                for (int qq = 0; qq < 4; ++qq) {
                    f32x4 g4 = {acc0[4 * qq], acc0[4 * qq + 1], acc0[4 * qq + 2], acc0[4 * qq + 3]};
                    hv0[qq] = bfu(lstm_ew1(g4, cS[0][qq]));
                }
#pragma unroll
                for (int qq = 0; qq < 4; ++qq) {
                    f32x4 g4 = {acc1[4 * qq], acc1[4 * qq + 1], acc1[4 * qq + 2], acc1[4 * qq + 3]};
                    hv1[qq] = bfu(lstm_ew1(g4, cS[1][qq]));
                }
                // deferred writes
#pragma unroll
                for (int qq = 0; qq < 4; ++qq) {
                    int k = 72 + 8 * wave + 2 * qq + hi;
                    *(ushort*)(sb + O_A2 + blk(10, 0, k >> 4, q) + eix(ln31, k & 15)) = hv0[qq];
                    *(ushort*)(sb + O_A2 + blk(10, 1, k >> 4, q) + eix(ln31, k & 15)) = hv1[qq];
                }
            }
        } else if (wave < 13) { // ---- LSTM3(t-1) + FC34(t-2) + y-stage ----
            const bool ystage = (wave >= 11) && (t <= 21);
            float4 yv[5];
            if (ystage) { // early global loads, hidden under L3 compute
                const int m = 32 * (wave - 11) + (lane >> 1);
                const float* yp = y + (size_t)(b0 + m) * 900 + (t + 3) * 36;
#pragma unroll
                for (int i = 0; i < 5; ++i) {
                    int c = 2 * i + (lane & 1);
                    if (c < 9) yv[i] = *(const float4*)(yp + 4 * c);
                }
            }
            ushort hv0[4], hv1[4];
            bf16x8 ahw0 = {}, ahw1 = {};
            if (t >= 1) {
                bf16x8 a[9], b[9];
                a[0] = *(const bf16x8*)(sb + O_A1 + blk(2, 0, 0, p) + (lane << 3));
                a[1] = *(const bf16x8*)(sb + O_A1 + blk(2, 0, 1, p) + (lane << 3));
#pragma unroll
                for (int i = 0; i < 5; ++i)
                    a[2 + i] = *(const bf16x8*)(sb + O_A2 + blk(10, 0, 4 + i, p) + (lane << 3));
                a[7] = *(const bf16x8*)(sb + O_AH3 + blk(2, 0, 0, p) + (lane << 3));
                a[8] = *(const bf16x8*)(sb + O_AH3 + blk(2, 0, 1, p) + (lane << 3));
                f32x16 acc0 = Z16;
#pragma unroll
                for (int i = 0; i < 9; ++i) acc0 = MFMA32(W[i], a[i], acc0, 0, 0, 0);
                b[0] = *(const bf16x8*)(sb + O_A1 + blk(2, 1, 0, p) + (lane << 3));
                b[1] = *(const bf16x8*)(sb + O_A1 + blk(2, 1, 1, p) + (lane << 3));
#pragma unroll
                for (int i = 0; i < 5; ++i)
                    b[2 + i] = *(const bf16x8*)(sb + O_A2 + blk(10, 1, 4 + i, p) + (lane << 3));
                b[7] = *(const bf16x8*)(sb + O_AH3 + blk(2, 1, 0, p) + (lane << 3));
                b[8] = *(const bf16x8*)(sb + O_AH3 + blk(2, 1, 1, p) + (lane << 3));
                f32x16 acc1 = Z16;
#pragma unroll
                for (int i = 0; i < 9; ++i) acc1 = MFMA32(W[i], b[i], acc1, 0, 0, 0);
                if (wave == 9)  { ahw0 = a[7]; ahw1 = a[8]; }
                if (wave == 10) { ahw0 = b[7]; ahw1 = b[8]; }
#pragma unroll
                for (int qq = 0; qq < 4; ++qq) {
                    f32x4 g4 = {acc0[4 * qq], acc0[4 * qq + 1], acc0[4 * qq + 2], acc0[4 * qq + 3]};
                    hv0[qq] = bfu(lstm_ew1(g4, cS[0][qq]));
                }
#pragma unroll
                for (int qq = 0; qq < 4; ++qq) {
                    f32x4 g4 = {acc1[4 * qq], acc1[4 * qq + 1], acc1[4 * qq + 2], acc1[4 * qq + 3]};
                    hv1[qq] = bfu(lstm_ew1(g4, cS[1][qq]));
                }
            }
            if (t >= 2 && wave < 11) { // FC34(t-2), AH3[p] frags reused from L3 loads
                const int ntw = wave - 9;
                f32x16 acc = Z16;
                acc = MFMA32(W[9], ahw0, acc, 0, 0, 0);
                acc = MFMA32(W[10], ahw1, acc, 0, 0, 0);
                float s0 = 0.f, s1 = 0.f;
#pragma unroll
                for (int qq = 0; qq < 2; ++qq) {
                    int r = 8 * qq + 4 * hi;
                    float4 b3v = *(const float4*)(b3 + r);
                    float4 w0v = *(const float4*)(W4 + r);
                    float4 w1v = *(const float4*)(W4 + 16 + r);
#pragma unroll
                    for (int s = 0; s < 4; ++s) {
                        float u = fmaxf(acc[4 * qq + s] + b3v[s], 0.f);
                        s0 = fmaf(u, w0v[s], s0);
                        s1 = fmaf(u, w1v[s], s1);
                    }
                }
                s0 += __shfl_xor(s0, 32); s1 += __shfl_xor(s1, 32);
                if (lane < 32) {
                    float2 o; o.x = s0 + b4[0]; o.y = s1 + b4[1];
                    *(float2*)(out + (size_t)(b0 + 32 * ntw + ln31) * 50 + (t - 2) * 2) = o;
                }
            }
            // deferred LDS writes
            if (t >= 1) {
                const int M3 = wave - 9;
#pragma unroll
                for (int qq = 0; qq < 4; ++qq) {
                    int k = 8 * M3 + 2 * qq + hi;
                    *(ushort*)(sb + O_AH3 + blk(2, 0, k >> 4, q) + eix(ln31, k & 15)) = hv0[qq];
                    *(ushort*)(sb + O_AH3 + blk(2, 1, k >> 4, q) + eix(ln31, k & 15)) = hv1[qq];
                }
            }
            if (ystage) {
                const int m = 32 * (wave - 11) + (lane >> 1);
#pragma unroll
                for (int i = 0; i < 5; ++i) {
                    int c = 2 * i + (lane & 1);
                    if (c < 9) {
                        ushort4 pk;
                        pk.x = bfu(yv[i].x); pk.y = bfu(yv[i].y);
                        pk.z = bfu(yv[i].z); pk.w = bfu(yv[i].w);
                        int k0 = 4 * c;
                        *(ushort4*)(sb + O_AY + blk(3, wave - 11, k0 >> 4, q) + eix(m & 31, k0 & 15)) = pk;
                    }
                }
            }
        } else { // ---- w13-15: L1(t) + FC2(t+1) + FC1(t+2) + x-stage ----
            float2 xv = {0.f, 0.f};
            if (wave == 13 && t <= 23)
                xv = *(const float2*)(x + (size_t)(b0 + lane) * 50 + (t + 1) * 2);
            ushort hva[4], hvb[4];
            if (t <= 24 && wave < 15) { // L1
                bf16x8 a0 = *(const bf16x8*)(sb + O_A1 + blk(2, 0, 0, p) + (lane << 3));
                bf16x8 a1 = *(const bf16x8*)(sb + O_A1 + blk(2, 0, 1, p) + (lane << 3));
                bf16x8 c0 = *(const bf16x8*)(sb + O_A1 + blk(2, 1, 0, p) + (lane << 3));
                bf16x8 c1 = *(const bf16x8*)(sb + O_A1 + blk(2, 1, 1, p) + (lane << 3));
                f32x16 acc0 = Z16, acc1 = Z16;
                acc0 = MFMA32(W[0], a0, acc0, 0, 0, 0);
                acc0 = MFMA32(W[1], a1, acc0, 0, 0, 0);
                acc1 = MFMA32(W[0], c0, acc1, 0, 0, 0);
                acc1 = MFMA32(W[1], c1, acc1, 0, 0, 0);
#pragma unroll
                for (int qq = 0; qq < 4; ++qq) {
                    f32x4 g4 = {acc0[4 * qq], acc0[4 * qq + 1], acc0[4 * qq + 2], acc0[4 * qq + 3]};
                    hva[qq] = bfu(lstm_ew1(g4, cS[0][qq]));
                }
#pragma unroll
                for (int qq = 0; qq < 4; ++qq) {
                    f32x4 g4 = {acc1[4 * qq], acc1[4 * qq + 1], acc1[4 * qq + 2], acc1[4 * qq + 3]};
                    hvb[qq] = bfu(lstm_ew1(g4, cS[1][qq]));
                }
            }
            ushort4 f1p[2][4];
            if (t <= 22 && wave >= 14) { // FC1(t+2)
#pragma unroll
                for (int nt = 0; nt < 2; ++nt) {
                    bf16x8 a0 = *(const bf16x8*)(sb + O_AY + blk(3, nt, 0, p) + (lane << 3));
                    bf16x8 a1 = *(const bf16x8*)(sb + O_AY + blk(3, nt, 1, p) + (lane << 3));
                    bf16x8 a2 = *(const bf16x8*)(sb + O_AY + blk(3, nt, 2, p) + (lane << 3));
                    f32x16 acc = Z16;
                    acc = MFMA32(W[7], a0, acc, 0, 0, 0);
                    acc = MFMA32(W[8], a1, acc, 0, 0, 0);
                    acc = MFMA32(W[9], a2, acc, 0, 0, 0);
#pragma unroll
                    for (int qq = 0; qq < 4; ++qq) {
                        ushort4 pk;
                        pk.x = bfu(fmaxf(acc[4 * qq + 0], 0.f));
                        pk.y = bfu(fmaxf(acc[4 * qq + 1], 0.f));
                        pk.z = bfu(fmaxf(acc[4 * qq + 2], 0.f));
                        pk.w = bfu(fmaxf(acc[4 * qq + 3], 0.f));
                        f1p[nt][qq] = pk;
                    }
                }
            }
            ushort4 f2p[2][4];
            if (t <= 23) { // FC2(t+1)
#pragma unroll
                for (int nt = 0; nt < 2; ++nt) {
                    bf16x8 a0 = *(const bf16x8*)(sb + O_AT1 + blk(5, nt, 0, p) + (lane << 3));
                    bf16x8 a1 = *(const bf16x8*)(sb + O_AT1 + blk(5, nt, 1, p) + (lane << 3));
                    bf16x8 a2 = *(const bf16x8*)(sb + O_AT1 + blk(5, nt, 2, p) + (lane << 3));
                    bf16x8 a3 = *(const bf16x8*)(sb + O_AT1 + blk(5, nt, 3, p) + (lane << 3));
                    bf16x8 a4 = *(const bf16x8*)(sb + O_AT1 + blk(5, nt, 4, p) + (lane << 3));
                    f32x16 acc = Z16;
                    acc = MFMA32(W[2], a0, acc, 0, 0, 0);
                    acc = MFMA32(W[3], a1, acc, 0, 0, 0);
                    acc = MFMA32(W[4], a2, acc, 0, 0, 0);
                    acc = MFMA32(W[5], a3, acc, 0, 0, 0);
                    acc = MFMA32(W[6], a4, acc, 0, 0, 0);
#pragma unroll
                    for (int qq = 0; qq < 4; ++qq) {
                        ushort4 pk;
                        pk.x = bfu(acc[4 * qq + 0]); pk.y = bfu(acc[4 * qq + 1]);
                        pk.z = bfu(acc[4 * qq + 2]); pk.w = bfu(acc[4 * qq + 3]);
                        f2p[nt][qq] = pk;
                    }
                }
            }
            // ===== deferred writes =====
            if (t <= 24 && wave < 15) {
                const int M1 = wave - 13;
#pragma unroll
                for (int qq = 0; qq < 4; ++qq) {
                    int k = 2 + 8 * M1 + 2 * qq + hi;
                    *(ushort*)(sb + O_A1 + blk(2, 0, k >> 4, q) + eix(ln31, k & 15)) = hva[qq];
                    *(ushort*)(sb + O_A1 + blk(2, 1, k >> 4, q) + eix(ln31, k & 15)) = hvb[qq];
                }
            }
            if (wave == 13 && t <= 23) {
                const int nt = lane >> 5;
                union { uint u; ushort s[2]; } xu;
                xu.s[0] = bfu(xv.x); xu.s[1] = bfu(xv.y);
                *(uint*)(sb + O_A1 + blk(2, nt, 0, q) + (ln31 << 3)) = xu.u;
            }
            if (t <= 22 && wave >= 14) {
#pragma unroll
                for (int nt = 0; nt < 2; ++nt)
#pragma unroll
                    for (int qq = 0; qq < 4; ++qq) {
                        int f0 = 32 * (wave - 14) + 8 * qq + 4 * hi;
                        *(ushort4*)(sb + O_AT1 + blk(5, nt, f0 >> 4, q) + eix(ln31, f0 & 15)) = f1p[nt][qq];
                    }
            }
            if (t <= 23) {
#pragma unroll
                for (int nt = 0; nt < 2; ++nt)
#pragma unroll
                    for (int qq = 0; qq < 4; ++qq) {
                        int n0 = 32 * (wave - 13) + 8 * qq + 4 * hi;
                        if (n0 < 72)
                            *(ushort4*)(sb + O_A2 + blk(10, nt, n0 >> 4, q) + eix(ln31, n0 & 15)) = f2p[nt][qq];
                    }
            }
        }
        __syncthreads();
    }

    // ---- epilogue: FC34 for t=24; h3(24) in AH3 slot 0 ----
    if (wave == 9 || wave == 10) {
        const int ntw = wave - 9;
        f32x16 acc = Z16;
#pragma unroll
        for (int i = 0; i < 2; ++i) {
            bf16x8 a = *(const bf16x8*)(sb + O_AH3 + blk(2, ntw, i, 0) + (lane << 3));
            acc = MFMA32(W[9 + i], a, acc, 0, 0, 0);
        }
        float s0 = 0.f, s1 = 0.f;
#pragma unroll
        for (int qq = 0; qq < 2; ++qq) {
            int r = 8 * qq + 4 * hi;
            float4 b3v = *(const float4*)(b3 + r);
            float4 w0v = *(const float4*)(W4 + r);
            float4 w1v = *(const float4*)(W4 + 16 + r);
#pragma unroll
            for (int s = 0; s < 4; ++s) {
                float u = fmaxf(acc[4 * qq + s] + b3v[s], 0.f);
                s0 = fmaf(u, w0v[s], s0);
                s1 = fmaf(u, w1v[s], s1);
            }
        }
        s0 += __shfl_xor(s0, 32); s1 += __shfl_xor(s1, 32);
        if (lane < 32) {
            float2 o; o.x = s0 + b4[0]; o.y = s1 + b4[1];
            *(float2*)(out + (size_t)(b0 + 32 * ntw + ln31) * 50 + 24 * 2) = o;
        }
    }
}

extern "C" void kernel_launch(void* const* d_in, const int* in_sizes, int n_in,
                              void* d_out, int out_size, void* d_ws, size_t ws_size,
                              hipStream_t stream) {
    (void)in_sizes; (void)n_in; (void)d_ws; (void)ws_size; (void)out_size;
    hipFuncSetAttribute((const void*)lstm_fused,
                        hipFuncAttributeMaxDynamicSharedMemorySize, LDS_BYTES);
    lstm_fused<<<dim3(2048), dim3(THREADS), LDS_BYTES, stream>>>(
        (const float*)d_in[0], (const float*)d_in[1],
        (const float*)d_in[2], (const float*)d_in[3],
        (const float*)d_in[4], (const float*)d_in[5],
        (const float*)d_in[6], (const float*)d_in[7],
        (const float*)d_in[8], (const float*)d_in[9],
        (const float*)d_in[10], (const float*)d_in[11],
        (const float*)d_in[12], (const float*)d_in[13],
        (const float*)d_in[14], (const float*)d_in[15],
        (const float*)d_in[16], (const float*)d_in[17],
        (const float*)d_in[18], (const float*)d_in[19],
        (const float*)d_in[20], (const float*)d_in[21],
        (float*)d_out);
}

// Round 13
// 879.087 us; speedup vs baseline: 1.9409x; 1.9409x over previous
//
#include <hip/hip_runtime.h>
#include <hip/hip_bf16.h>

#define THREADS 1024

typedef __hip_bfloat16 bf16;
typedef __attribute__((ext_vector_type(4))) float f32x4;
typedef __attribute__((ext_vector_type(16))) float f32x16;
typedef __attribute__((ext_vector_type(8))) short bf16x8;

#define MFMA32 __builtin_amdgcn_mfma_f32_32x32x16_bf16
#define Z16 f32x16{0.f,0.f,0.f,0.f,0.f,0.f,0.f,0.f,0.f,0.f,0.f,0.f,0.f,0.f,0.f,0.f}

// ---- LDS: blocks of 512 bf16 = one 32-col x 16-k B-fragment tile.
// Buffers double-slotted: read slot p=t&1, write slot q=p^1.
#define O_A1  0       // 2nt x 2kc x 2s : K=[x(2)|h1(16)|bias@18|pad]
#define O_AY  4096    // 2nt x 3kc x 2s : K=[y(36)|bias@36|pad]
#define O_AT1 10240   // 2nt x 5kc x 2s : K=[t1(64)|bias@64|pad]
#define O_A2  20480   // 2nt x 10kc x 2s: K=[l2(72)|h2(72)|bias@144|pad]
#define O_AH3 40960   // 2nt x 2kc x 2s : K=h3(32)
#define LDS_ELEMS 45056
#define LDS_BYTES (LDS_ELEMS * 2)   // 90112

__device__ __forceinline__ int blk(int KC, int nt, int kc, int slot) {
    return ((nt * KC + kc) * 2 + slot) << 9;
}
__device__ __forceinline__ int eix(int col, int kl) { // elem index in block
    return ((col | ((kl >> 3) << 5)) << 3) + (kl & 7);
}

__device__ __forceinline__ float rcp_(float x) { return __builtin_amdgcn_rcpf(x); }
__device__ __forceinline__ float exp2_(float x) {
#if __has_builtin(__builtin_amdgcn_exp2f)
    return __builtin_amdgcn_exp2f(x);
#else
    return exp2f(x);
#endif
}

// gate EW, log2e folded into weights: a = {-i*log2e, -f*log2e, 2g*log2e, -o*log2e}
__device__ __forceinline__ float lstm_ew1(f32x4 a, float& cst) {
    float ei = exp2_(a[0]);
    float ef = exp2_(a[1]);
    float eg = exp2_(fminf(a[2], 115.0f));
    float eo = exp2_(a[3]);
    float c = rcp_(1.0f + ef) * cst + (eg - 1.0f) * rcp_((1.0f + ei) * (eg + 1.0f));
    cst = c;
    float ec = exp2_(fminf(c * 2.885390082f, 115.0f));
    return (ec - 1.0f) * rcp_((1.0f + eo) * (ec + 1.0f));
}

__device__ __forceinline__ ushort bfu(float f) {
    union { bf16 b; ushort u; } v; v.b = __float2bfloat16(f); return v.u;
}

// pack one K=16 weight fragment; k-map k = ((lane>>5)<<3)+j, rows = lane&31
template <typename F>
__device__ __forceinline__ bf16x8 mk32(int lane, F val) { // val(k), k in [0,16)
    union { bf16x8 v; bf16 h[8]; } u;
#pragma unroll
    for (int j = 0; j < 8; ++j)
        u.h[j] = __float2bfloat16(val(((lane >> 5) << 3) + j));
    return u.v;
}

__global__ void __launch_bounds__(THREADS, 4)
lstm_fused(const float* __restrict__ x, const float* __restrict__ y,
           const float* __restrict__ Wih1, const float* __restrict__ Whh1,
           const float* __restrict__ bih1, const float* __restrict__ bhh1,
           const float* __restrict__ Wih2, const float* __restrict__ Whh2,
           const float* __restrict__ bih2, const float* __restrict__ bhh2,
           const float* __restrict__ Wih3, const float* __restrict__ Whh3,
           const float* __restrict__ bih3, const float* __restrict__ bhh3,
           const float* __restrict__ W1, const float* __restrict__ b1,
           const float* __restrict__ W2, const float* __restrict__ b2,
           const float* __restrict__ W3, const float* __restrict__ b3,
           const float* __restrict__ W4, const float* __restrict__ b4,
           float* __restrict__ out) {
    extern __shared__ char smem[];
    bf16* sb = (bf16*)smem;
    const int tid = threadIdx.x;
    const int wave = tid >> 6, lane = tid & 63;
    const int ln31 = lane & 31, hi = lane >> 5;
    const int b0 = blockIdx.x * 64;

    // ---- roles (same as r11) ----
    bf16x8 W[11];
#pragma unroll
    for (int i = 0; i < 11; ++i) W[i] = bf16x8{0, 0, 0, 0, 0, 0, 0, 0};

    if (wave < 9) { // LSTM2 rows n=32w+ln31, gate interleave n=4h+g, log2e folded
        int n = 32 * wave + ln31;
        int r = (n & 3) * 72 + (n >> 2);
        float bias = bih2[r] + bhh2[r];
        float sc = ((n & 3) == 2) ? 2.885390082f : -1.442695041f;
#pragma unroll
        for (int kc = 0; kc < 10; ++kc)
            W[kc] = mk32(lane, [&](int k) {
                int kg = kc * 16 + k;
                float v = kg < 72 ? Wih2[r * 72 + kg]
                       : (kg < 144 ? Whh2[r * 72 + (kg - 72)]
                       : (kg == 144 ? bias : 0.0f));
                return sc * v; });
    } else if (wave < 13) { // LSTM3, log2e folded
        int n = 32 * (wave - 9) + ln31;
        int r = (n & 3) * 32 + (n >> 2);
        float bias = bih3[r] + bhh3[r];
        float sc = ((n & 3) == 2) ? 2.885390082f : -1.442695041f;
        W[0] = mk32(lane, [&](int k) {
            return sc * (k < 2 ? 0.0f : Wih3[r * 88 + (k - 2)]); });
        W[1] = mk32(lane, [&](int k) {
            int kg = 16 + k;
            return sc * (kg < 18 ? Wih3[r * 88 + (kg - 2)] : (kg == 18 ? bias : 0.0f)); });
#pragma unroll
        for (int i = 0; i < 5; ++i)
            W[2 + i] = mk32(lane, [&](int k) {
                int kg = 64 + i * 16 + k;
                return sc * (kg < 72 ? 0.0f : Wih3[r * 88 + 16 + (kg - 72)]); });
#pragma unroll
        for (int i = 0; i < 2; ++i)
            W[7 + i] = mk32(lane, [&](int k) { return sc * Whh3[r * 32 + i * 16 + k]; });
        if (wave < 11) { // FC34 (unscaled)
#pragma unroll
            for (int i = 0; i < 2; ++i)
                W[9 + i] = mk32(lane, [&](int k) {
                    return (ln31 < 16) ? W3[ln31 * 32 + i * 16 + k] : 0.0f; });
        }
    } else {
        if (wave < 15) { // L1 Mtile wave-13, log2e folded
            int n = 32 * (wave - 13) + ln31;
            int r = (n & 3) * 16 + (n >> 2);
            float bias = bih1[r] + bhh1[r];
            float sc = ((n & 3) == 2) ? 2.885390082f : -1.442695041f;
            W[0] = mk32(lane, [&](int k) {
                return sc * (k < 2 ? Wih1[r * 2 + k] : Whh1[r * 16 + (k - 2)]); });
            W[1] = mk32(lane, [&](int k) {
                int kg = 16 + k;
                return sc * (kg < 18 ? Whh1[r * 16 + (kg - 2)] : (kg == 18 ? bias : 0.0f)); });
        }
        { // FC2 Mtile wave-13 (unscaled)
            int n2 = 32 * (wave - 13) + ln31;
#pragma unroll
            for (int kc = 0; kc < 5; ++kc)
                W[2 + kc] = mk32(lane, [&](int k) {
                    int kg = kc * 16 + k;
                    if (n2 >= 72) return 0.0f;
                    return kg < 64 ? W2[n2 * 64 + kg] : (kg == 64 ? b2[n2] : 0.0f); });
        }
        if (wave >= 14) { // FC1 Mtile wave-14 (unscaled)
            int f = 32 * (wave - 14) + ln31;
#pragma unroll
            for (int kc = 0; kc < 3; ++kc)
                W[7 + kc] = mk32(lane, [&](int k) {
                    int kg = kc * 16 + k;
                    return kg < 36 ? W1[f * 36 + kg] : (kg == 36 ? b1[f] : 0.0f); });
        }
    }

    // ---- zero LDS ----
    {
        int4* z = (int4*)sb;
        int4 zv = {0, 0, 0, 0};
        for (int i = tid; i < LDS_BYTES / 16; i += THREADS) z[i] = zv;
    }
    __syncthreads();
    // ---- stage y(0)->AY[s0], y(1)->AY[s1], x(0)->A1[s0], bias lanes ----
    for (int it = tid; it < 2 * 2304; it += THREADS) {
        int slot = it / 2304, r2 = it - slot * 2304;
        int m = r2 / 36, k = r2 - m * 36;
        sb[O_AY + blk(3, m >> 5, k >> 4, slot) + eix(m & 31, k & 15)] =
            __float2bfloat16(y[(size_t)(b0 + m) * 900 + slot * 36 + k]);
    }
    if (tid < 128) {
        int m = tid >> 1, k = tid & 1;
        sb[O_A1 + blk(2, m >> 5, 0, 0) + eix(m & 31, k)] =
            __float2bfloat16(x[(size_t)(b0 + m) * 50 + k]);
    }
    {
        const bf16 one = __float2bfloat16(1.0f);
        int i = tid & 127, col = i & 31, nt = (i >> 5) & 1, s = (i >> 6) & 1;
        if (tid < 128)       sb[O_A1 + blk(2, nt, 1, s) + eix(col, 2)] = one;   // k=18
        else if (tid < 256)  sb[O_AY + blk(3, nt, 2, s) + eix(col, 4)] = one;   // k=36
        else if (tid < 384)  sb[O_AT1 + blk(5, nt, 4, s) + eix(col, 0)] = one;  // k=64
        else if (tid < 512)  sb[O_A2 + blk(10, nt, 9, s) + eix(col, 0)] = one;  // k=144
    }
    __syncthreads();
    // ---- prologue FC1(0)->AT1[1], FC1(1)->AT1[0] on w14-15 ----
    if (wave >= 14) {
#pragma unroll
        for (int s = 0; s < 2; ++s) {
#pragma unroll
            for (int nt = 0; nt < 2; ++nt) {
                f32x16 acc = Z16;
#pragma unroll
                for (int kc = 0; kc < 3; ++kc) {
                    bf16x8 a = *(const bf16x8*)(sb + O_AY + blk(3, nt, kc, s) + (lane << 3));
                    acc = MFMA32(W[7 + kc], a, acc, 0, 0, 0);
                }
#pragma unroll
                for (int qq = 0; qq < 4; ++qq) {
                    int f0 = 32 * (wave - 14) + 8 * qq + 4 * hi;
                    ushort4 pk;
                    pk.x = bfu(fmaxf(acc[4 * qq + 0], 0.f));
                    pk.y = bfu(fmaxf(acc[4 * qq + 1], 0.f));
                    pk.z = bfu(fmaxf(acc[4 * qq + 2], 0.f));
                    pk.w = bfu(fmaxf(acc[4 * qq + 3], 0.f));
                    *(ushort4*)(sb + O_AT1 + blk(5, nt, f0 >> 4, s ^ 1) + eix(ln31, f0 & 15)) = pk;
                }
            }
        }
    }
    __syncthreads();
    // ---- prologue FC2(0)->A2[s0] (w13-15, reads AT1[s1]); y(2)->AY[s0] (w11-12) ----
    if (wave >= 13) {
#pragma unroll
        for (int nt = 0; nt < 2; ++nt) {
            f32x16 acc = Z16;
#pragma unroll
            for (int kc = 0; kc < 5; ++kc) {
                bf16x8 a = *(const bf16x8*)(sb + O_AT1 + blk(5, nt, kc, 1) + (lane << 3));
                acc = MFMA32(W[2 + kc], a, acc, 0, 0, 0);
            }
#pragma unroll
            for (int qq = 0; qq < 4; ++qq) {
                int n0 = 32 * (wave - 13) + 8 * qq + 4 * hi;
                if (n0 < 72) {
                    ushort4 pk;
                    pk.x = bfu(acc[4 * qq + 0]); pk.y = bfu(acc[4 * qq + 1]);
                    pk.z = bfu(acc[4 * qq + 2]); pk.w = bfu(acc[4 * qq + 3]);
                    *(ushort4*)(sb + O_A2 + blk(10, nt, n0 >> 4, 0) + eix(ln31, n0 & 15)) = pk;
                }
            }
        }
    } else if (wave == 11 || wave == 12) {
        const int half = wave - 11;
        const int m = 32 * half + (lane >> 1);
        const float* yp = y + (size_t)(b0 + m) * 900 + 2 * 36;
#pragma unroll
        for (int c = (lane & 1); c < 9; c += 2) {
            float4 v = *(const float4*)(yp + 4 * c);
            ushort4 pk;
            pk.x = bfu(v.x); pk.y = bfu(v.y); pk.z = bfu(v.z); pk.w = bfu(v.w);
            int k0 = 4 * c;
            *(ushort4*)(sb + O_AY + blk(3, half, k0 >> 4, 0) + eix(m & 31, k0 & 15)) = pk;
        }
    }
    float cS[2][4] = {};
    __syncthreads();

    // ======== main loop: ONE barrier per phase (r11 structure) ========
    for (int t = 0; t <= 25; ++t) {
        const int p = t & 1, q = p ^ 1;

        if (wave < 9) { // ---- LSTM2(t), t<=24 ----
            if (t <= 24) {
#pragma unroll
                for (int nt = 0; nt < 2; ++nt) {
                    f32x16 acc = Z16;
#pragma unroll
                    for (int kc = 0; kc < 10; ++kc) {
                        bf16x8 a = *(const bf16x8*)(sb + O_A2 + blk(10, nt, kc, p) + (lane << 3));
                        acc = MFMA32(W[kc], a, acc, 0, 0, 0);
                    }
#pragma unroll
                    for (int qq = 0; qq < 4; ++qq) {
                        f32x4 g4 = {acc[4 * qq], acc[4 * qq + 1], acc[4 * qq + 2], acc[4 * qq + 3]};
                        float hv = lstm_ew1(g4, cS[nt][qq]);
                        int k = 72 + 8 * wave + 2 * qq + hi;
                        sb[O_A2 + blk(10, nt, k >> 4, q) + eix(ln31, k & 15)] = __float2bfloat16(hv);
                    }
                }
            }
        } else if (wave < 13) { // ---- LSTM3(t-1) + FC34(t-2) + y-stage ----
            const bool ystage = (wave >= 11) && (t <= 21);
            float4 yv[5];
            if (ystage) { // early loads: HBM latency hides under L3 MFMA below
                const int m = 32 * (wave - 11) + (lane >> 1);
                const float* yp = y + (size_t)(b0 + m) * 900 + (t + 3) * 36;
#pragma unroll
                for (int i = 0; i < 5; ++i) {
                    int c = 2 * i + (lane & 1);
                    if (c < 9) yv[i] = *(const float4*)(yp + 4 * c);
                }
            }
            if (t >= 1) {
                const int M3 = wave - 9;
#pragma unroll
                for (int nt = 0; nt < 2; ++nt) {
                    f32x16 acc = Z16;
                    {
                        bf16x8 a0 = *(const bf16x8*)(sb + O_A1 + blk(2, nt, 0, p) + (lane << 3));
                        acc = MFMA32(W[0], a0, acc, 0, 0, 0);
                        bf16x8 a1 = *(const bf16x8*)(sb + O_A1 + blk(2, nt, 1, p) + (lane << 3));
                        acc = MFMA32(W[1], a1, acc, 0, 0, 0);
                    }
#pragma unroll
                    for (int i = 0; i < 5; ++i) {
                        bf16x8 a = *(const bf16x8*)(sb + O_A2 + blk(10, nt, 4 + i, p) + (lane << 3));
                        acc = MFMA32(W[2 + i], a, acc, 0, 0, 0);
                    }
#pragma unroll
                    for (int i = 0; i < 2; ++i) {
                        bf16x8 a = *(const bf16x8*)(sb + O_AH3 + blk(2, nt, i, p) + (lane << 3));
                        acc = MFMA32(W[7 + i], a, acc, 0, 0, 0);
                    }
#pragma unroll
                    for (int qq = 0; qq < 4; ++qq) {
                        f32x4 g4 = {acc[4 * qq], acc[4 * qq + 1], acc[4 * qq + 2], acc[4 * qq + 3]};
                        float hv = lstm_ew1(g4, cS[nt][qq]);
                        int k = 8 * M3 + 2 * qq + hi;
                        sb[O_AH3 + blk(2, nt, k >> 4, q) + eix(ln31, k & 15)] = __float2bfloat16(hv);
                    }
                }
            }
            if (wave < 11) { // FC34(t-2), Nt = wave-9
                if (t >= 2) {
                    const int ntw = wave - 9;
                    f32x16 acc = Z16;
#pragma unroll
                    for (int i = 0; i < 2; ++i) {
                        bf16x8 a = *(const bf16x8*)(sb + O_AH3 + blk(2, ntw, i, p) + (lane << 3));
                        acc = MFMA32(W[9 + i], a, acc, 0, 0, 0);
                    }
                    float s0 = 0.f, s1 = 0.f;
#pragma unroll
                    for (int qq = 0; qq < 2; ++qq) {
                        int r = 8 * qq + 4 * hi;
                        float4 b3v = *(const float4*)(b3 + r);
                        float4 w0v = *(const float4*)(W4 + r);
                        float4 w1v = *(const float4*)(W4 + 16 + r);
#pragma unroll
                        for (int s = 0; s < 4; ++s) {
                            float u = fmaxf(acc[4 * qq + s] + b3v[s], 0.f);
                            s0 = fmaf(u, w0v[s], s0);
                            s1 = fmaf(u, w1v[s], s1);
                        }
                    }
                    s0 += __shfl_xor(s0, 32); s1 += __shfl_xor(s1, 32);
                    if (lane < 32) {
                        float2 o; o.x = s0 + b4[0]; o.y = s1 + b4[1];
                        *(float2*)(out + (size_t)(b0 + 32 * ntw + ln31) * 50 + (t - 2) * 2) = o;
                    }
                }
            } else if (ystage) { // y(t+3) writes (loads issued at phase top)
                const int m = 32 * (wave - 11) + (lane >> 1);
#pragma unroll
                for (int i = 0; i < 5; ++i) {
                    int c = 2 * i + (lane & 1);
                    if (c < 9) {
                        ushort4 pk;
                        pk.x = bfu(yv[i].x); pk.y = bfu(yv[i].y);
                        pk.z = bfu(yv[i].z); pk.w = bfu(yv[i].w);
                        int k0 = 4 * c;
                        *(ushort4*)(sb + O_AY + blk(3, wave - 11, k0 >> 4, q) + eix(m & 31, k0 & 15)) = pk;
                    }
                }
            }
        } else { // ---- w13-15: L1(t) + FC2(t+1) + FC1(t+2) + x-stage ----
            if (t <= 24 && wave < 15) { // L1, Mtile wave-13
                const int M1 = wave - 13;
#pragma unroll
                for (int nt = 0; nt < 2; ++nt) {
                    f32x16 acc = Z16;
#pragma unroll
                    for (int i = 0; i < 2; ++i) {
                        bf16x8 a = *(const bf16x8*)(sb + O_A1 + blk(2, nt, i, p) + (lane << 3));
                        acc = MFMA32(W[i], a, acc, 0, 0, 0);
                    }
#pragma unroll
                    for (int qq = 0; qq < 4; ++qq) {
                        f32x4 g4 = {acc[4 * qq], acc[4 * qq + 1], acc[4 * qq + 2], acc[4 * qq + 3]};
                        float hv = lstm_ew1(g4, cS[nt][qq]);
                        int k = 2 + 8 * M1 + 2 * qq + hi;
                        sb[O_A1 + blk(2, nt, k >> 4, q) + eix(ln31, k & 15)] = __float2bfloat16(hv);
                    }
                }
            }
            if (t <= 23 && wave == 13) { // x(t+1) -> A1[q]
                const int nt = lane >> 5;
                float2 xv = *(const float2*)(x + (size_t)(b0 + lane) * 50 + (t + 1) * 2);
                union { uint u; ushort s[2]; } xu;
                xu.s[0] = bfu(xv.x); xu.s[1] = bfu(xv.y);
                *(uint*)(sb + O_A1 + blk(2, nt, 0, q) + (ln31 << 3)) = xu.u;
            }
            if (t <= 22 && wave >= 14) { // FC1(t+2), Mtile wave-14
#pragma unroll
                for (int nt = 0; nt < 2; ++nt) {
                    f32x16 acc = Z16;
#pragma unroll
                    for (int kc = 0; kc < 3; ++kc) {
                        bf16x8 a = *(const bf16x8*)(sb + O_AY + blk(3, nt, kc, p) + (lane << 3));
                        acc = MFMA32(W[7 + kc], a, acc, 0, 0, 0);
                    }
#pragma unroll
                    for (int qq = 0; qq < 4; ++qq) {
                        int f0 = 32 * (wave - 14) + 8 * qq + 4 * hi;
                        ushort4 pk;
                        pk.x = bfu(fmaxf(acc[4 * qq + 0], 0.f));
                        pk.y = bfu(fmaxf(acc[4 * qq + 1], 0.f));
                        pk.z = bfu(fmaxf(acc[4 * qq + 2], 0.f));
                        pk.w = bfu(fmaxf(acc[4 * qq + 3], 0.f));
                        *(ushort4*)(sb + O_AT1 + blk(5, nt, f0 >> 4, q) + eix(ln31, f0 & 15)) = pk;
                    }
                }
            }
            if (t <= 23) { // FC2(t+1), Mtile wave-13
#pragma unroll
                for (int nt = 0; nt < 2; ++nt) {
                    f32x16 acc = Z16;
#pragma unroll
                    for (int kc = 0; kc < 5; ++kc) {
                        bf16x8 a = *(const bf16x8*)(sb + O_AT1 + blk(5, nt, kc, p) + (lane << 3));
                        acc = MFMA32(W[2 + kc], a, acc, 0, 0, 0);
                    }
#pragma unroll
                    for (int qq = 0; qq < 4; ++qq) {
                        int n0 = 32 * (wave - 13) + 8 * qq + 4 * hi;
                        if (n0 < 72) {
                            ushort4 pk;
                            pk.x = bfu(acc[4 * qq + 0]); pk.y = bfu(acc[4 * qq + 1]);
                            pk.z = bfu(acc[4 * qq + 2]); pk.w = bfu(acc[4 * qq + 3]);
                            *(ushort4*)(sb + O_A2 + blk(10, nt, n0 >> 4, q) + eix(ln31, n0 & 15)) = pk;
                        }
                    }
                }
            }
        }
        __syncthreads();
    }

    // ---- epilogue: FC34 for t=24; h3(24) in AH3 slot 0 ----
    if (wave == 9 || wave == 10) {
        const int ntw = wave - 9;
        f32x16 acc = Z16;
#pragma unroll
        for (int i = 0; i < 2; ++i) {
            bf16x8 a = *(const bf16x8*)(sb + O_AH3 + blk(2, ntw, i, 0) + (lane << 3));
            acc = MFMA32(W[9 + i], a, acc, 0, 0, 0);
        }
        float s0 = 0.f, s1 = 0.f;
#pragma unroll
        for (int qq = 0; qq < 2; ++qq) {
            int r = 8 * qq + 4 * hi;
            float4 b3v = *(const float4*)(b3 + r);
            float4 w0v = *(const float4*)(W4 + r);
            float4 w1v = *(const float4*)(W4 + 16 + r);
#pragma unroll
            for (int s = 0; s < 4; ++s) {
                float u = fmaxf(acc[4 * qq + s] + b3v[s], 0.f);
                s0 = fmaf(u, w0v[s], s0);
                s1 = fmaf(u, w1v[s], s1);
            }
        }
        s0 += __shfl_xor(s0, 32); s1 += __shfl_xor(s1, 32);
        if (lane < 32) {
            float2 o; o.x = s0 + b4[0]; o.y = s1 + b4[1];
            *(float2*)(out + (size_t)(b0 + 32 * ntw + ln31) * 50 + 24 * 2) = o;
        }
    }
}

extern "C" void kernel_launch(void* const* d_in, const int* in_sizes, int n_in,
                              void* d_out, int out_size, void* d_ws, size_t ws_size,
                              hipStream_t stream) {
    (void)in_sizes; (void)n_in; (void)d_ws; (void)ws_size; (void)out_size;
    hipFuncSetAttribute((const void*)lstm_fused,
                        hipFuncAttributeMaxDynamicSharedMemorySize, LDS_BYTES);
    lstm_fused<<<dim3(2048), dim3(THREADS), LDS_BYTES, stream>>>(
        (const float*)d_in[0], (const float*)d_in[1],
        (const float*)d_in[2], (const float*)d_in[3],
        (const float*)d_in[4], (const float*)d_in[5],
        (const float*)d_in[6], (const float*)d_in[7],
        (const float*)d_in[8], (const float*)d_in[9],
        (const float*)d_in[10], (const float*)d_in[11],
        (const float*)d_in[12], (const float*)d_in[13],
        (const float*)d_in[14], (const float*)d_in[15],
        (const float*)d_in[16], (const float*)d_in[17],
        (const float*)d_in[18], (const float*)d_in[19],
        (const float*)d_in[20], (const float*)d_in[21],
        (float*)d_out);
}